// Round 5
// baseline (222.782 us; speedup 1.0000x reference)
//
#include <hip/hip_runtime.h>
#include <math.h>

#define C 64
#define R 32
#define CUTOFF 5.0f
#define PI_F 3.14159265358979323846f

typedef __attribute__((ext_vector_type(8))) short short8b;
typedef __attribute__((ext_vector_type(4))) short short4b;
typedef __attribute__((ext_vector_type(4))) float f32x4;

#define LDS_FENCE() asm volatile("s_waitcnt lgkmcnt(0)" ::: "memory")

__device__ __forceinline__ float silu(float x) { return x / (1.0f + __expf(-x)); }

__device__ __forceinline__ unsigned short f2bfu(float x) {
  unsigned u = __builtin_bit_cast(unsigned, x);
  u += 0x7FFF + ((u >> 16) & 1);           // round-to-nearest-even
  return (unsigned short)(u >> 16);
}
__device__ __forceinline__ float bfu2f(unsigned short s) {
  return __builtin_bit_cast(float, (unsigned)s << 16);
}
__device__ __forceinline__ float bflo(unsigned u) {
  return __builtin_bit_cast(float, u << 16);
}
__device__ __forceinline__ float bfhi(unsigned u) {
  return __builtin_bit_cast(float, u & 0xffff0000u);
}

// ---------------------------------------------------------------------------
// Fused: histogram by src (blocks [0,histB)) + weight-fragment prep (rest).
// Wf[(kstep*ntiles + ntile)*64 + lane][8] bf16 MFMA B-frags.
// ---------------------------------------------------------------------------
__global__ __launch_bounds__(256) void k_misc(
    const int* __restrict__ ei, int* __restrict__ deg, int E, int histB,
    const float* __restrict__ W1, const float* __restrict__ W2,
    const float* __restrict__ W3, unsigned short* __restrict__ Wf) {
  if ((int)blockIdx.x < histB) {
    int e = blockIdx.x * 256 + threadIdx.x;
    if (e < E) atomicAdd(&deg[ei[e]], 1);
    return;
  }
  int id = (blockIdx.x - histB) * 256 + threadIdx.x;
  if (id >= 34816) return;
  const float* W; int ntiles, Nout, id2;
  if (id < 2048)       { W = W1; ntiles = 4;  Nout = 64;  id2 = id; }
  else if (id < 10240) { W = W2; ntiles = 8;  Nout = 128; id2 = id - 2048; }
  else                 { W = W3; ntiles = 12; Nout = 192; id2 = id - 10240; }
  int i = id2 & 7;
  int l = (id2 >> 3) & 63;
  int t = id2 >> 9;
  int nt = t % ntiles, ks = t / ntiles;
  int k = ks * 32 + ((l >> 4) << 2) + (i & 3) + ((i >> 2) << 4);
  int n = nt * 16 + (l & 15);
  Wf[id] = f2bfu(W[(size_t)k * Nout + n]);
}

// ---------------------------------------------------------------------------
// Node prep: Xn = X/(||X||^2+1); decompose -> 10 comps; mix with Wt[0..2].
// Outputs: Xn[N][9][C], nf32[N][C][12] fp32 (epilogue), nfh[N][C][6] dwords
// of packed bf16 pairs (gather path).
// ---------------------------------------------------------------------------
__global__ __launch_bounds__(256) void k_node_prep(
    const float* __restrict__ X, const float* __restrict__ Wt,
    float* __restrict__ Xn, float* __restrict__ nf32,
    unsigned* __restrict__ nfh, int N) {
  const int ln = threadIdx.x >> 6;
  const int c  = threadIdx.x & 63;
  const int node = blockIdx.x * 4 + ln;
  __shared__ float comps[4][C][12];

  if (node < N) {
    const float* xp = X + ((size_t)node * C + c) * 9;
    float x[9]; float nrm = 0.f;
#pragma unroll
    for (int j = 0; j < 9; j++) { x[j] = xp[j]; nrm += x[j] * x[j]; }
    const float inv = 1.0f / (nrm + 1.0f);
#pragma unroll
    for (int j = 0; j < 9; j++) x[j] *= inv;
    float* xnp = Xn + (size_t)node * 576 + c;
#pragma unroll
    for (int j = 0; j < 9; j++) xnp[j * 64] = x[j];
    const float tr3 = (x[0] + x[4] + x[8]) * (1.f / 3.f);
    float* cp = comps[ln][c];
    cp[0] = tr3;
    cp[1] = 0.5f * (x[1] - x[3]);
    cp[2] = 0.5f * (x[2] - x[6]);
    cp[3] = 0.5f * (x[5] - x[7]);
    cp[4] = x[0] - tr3;
    cp[5] = x[4] - tr3;
    cp[6] = x[8] - tr3;
    cp[7] = 0.5f * (x[1] + x[3]);
    cp[8] = 0.5f * (x[2] + x[6]);
    cp[9] = 0.5f * (x[5] + x[7]);
  }
  __syncthreads();
  if (node < N) {
    const float* W0 = Wt;
    const float* W1 = Wt + C * C;
    const float* W2 = Wt + 2 * C * C;
    float o[10];
#pragma unroll
    for (int j = 0; j < 10; j++) o[j] = 0.f;
    for (int k = 0; k < C; k++) {
      const float w0 = W0[k * C + c];
      const float w1 = W1[k * C + c];
      const float w2 = W2[k * C + c];
      const float4* cq = (const float4*)comps[ln][k];
      float4 q0 = cq[0], q1 = cq[1];
      float2 q2 = *(const float2*)(comps[ln][k] + 8);
      o[0] += q0.x * w0;
      o[1] += q0.y * w1; o[2] += q0.z * w1; o[3] += q0.w * w1;
      o[4] += q1.x * w2; o[5] += q1.y * w2; o[6] += q1.z * w2;
      o[7] += q1.w * w2; o[8] += q2.x * w2; o[9] += q2.y * w2;
    }
    float* np_ = nf32 + (size_t)node * 768 + c * 12;
    *(float4*)np_       = make_float4(o[0], o[1], o[2], o[3]);
    *(float4*)(np_ + 4) = make_float4(o[4], o[5], o[6], o[7]);
    *(float4*)(np_ + 8) = make_float4(o[8], o[9], 0.f, 0.f);
    unsigned* hp = nfh + (size_t)node * 384 + c * 6;
    unsigned d0 = (unsigned)f2bfu(o[0]) | ((unsigned)f2bfu(o[1]) << 16);
    unsigned d1 = (unsigned)f2bfu(o[2]) | ((unsigned)f2bfu(o[3]) << 16);
    unsigned d2 = (unsigned)f2bfu(o[4]) | ((unsigned)f2bfu(o[5]) << 16);
    unsigned d3 = (unsigned)f2bfu(o[6]) | ((unsigned)f2bfu(o[7]) << 16);
    unsigned d4 = (unsigned)f2bfu(o[8]) | ((unsigned)f2bfu(o[9]) << 16);
    *(uint2*)hp       = make_uint2(d0, d1);
    *(uint2*)(hp + 2) = make_uint2(d2, d3);
    *(uint2*)(hp + 4) = make_uint2(d4, 0u);
  }
}

// ---------------------------------------------------------------------------
// CSR build.
// ---------------------------------------------------------------------------
__global__ __launch_bounds__(1024) void k_scan(const int* __restrict__ deg,
                                               int* __restrict__ off,
                                               int* __restrict__ cur, int N) {
  __shared__ int sums[1024];
  const int t = threadIdx.x;
  const int L = (N + 1023) / 1024;
  const int base = t * L;
  int s = 0;
  for (int j = 0; j < L; j++) if (base + j < N) s += deg[base + j];
  sums[t] = s;
  __syncthreads();
  for (int d = 1; d < 1024; d <<= 1) {
    int v = (t >= d) ? sums[t - d] : 0;
    __syncthreads();
    sums[t] += v;
    __syncthreads();
  }
  int run = (t > 0) ? sums[t - 1] : 0;
  for (int j = 0; j < L; j++) {
    int i = base + j;
    if (i < N) { off[i] = run; run += deg[i]; cur[i] = 0; }
  }
  if (t == 1023) off[N] = sums[1023];
}

__global__ __launch_bounds__(256) void k_fill(const int* __restrict__ ei,
                                              const int* __restrict__ off,
                                              int* __restrict__ cur,
                                              int* __restrict__ elist,
                                              int* __restrict__ dlist, int E) {
  int e = blockIdx.x * 256 + threadIdx.x;
  if (e < E) {
    int s = ei[e];
    int d = ei[E + e];
    int pos = off[s] + atomicAdd(&cur[s], 1);
    elist[pos] = e;
    dlist[pos] = d;
  }
}

// ---------------------------------------------------------------------------
// Edge MLP via MFMA bf16 (fp32 accum), CSR edge order. Block = 4 independent
// waves, each owning 16 edges and a private LDS region (no __syncthreads;
// cross-lane LDS visibility via s_waitcnt lgkmcnt(0) fences).
// Output fa[p][64][4] bf16 = (f0,f1,f2,0), p = CSR position (sequential!).
// ---------------------------------------------------------------------------
__global__ __launch_bounds__(256) void k_mlp(
    const float* __restrict__ ew, const float* __restrict__ ea,
    const float* __restrict__ b1, const float* __restrict__ b2,
    const float* __restrict__ b3, const unsigned short* __restrict__ Wf,
    const int* __restrict__ elist, unsigned short* __restrict__ fa, int E) {
  __shared__ __align__(16) unsigned short pwall[4 * 3968];
  __shared__ float cws[4][16];
  const int tid = threadIdx.x;
  const int wv = tid >> 6, l = tid & 63;
  const int p0 = blockIdx.x * 64 + wv * 16;
  unsigned short* baseW = &pwall[wv * 3968];
  unsigned short* attrW = baseW;          // [16][40]
  unsigned short* h1W   = baseW + 640;    // [16][72]
  unsigned short* h2W   = baseW + 1792;   // [16][136]
  unsigned short* h3W   = baseW;          // [16][200] alias

  { // stage edge_attr (CSR order) -> bf16 LDS (4 lanes/edge)
    int el = l >> 2, q = l & 3;
    int p = p0 + el;
    uint4 pk = make_uint4(0, 0, 0, 0);
    if (p < E) {
      int orig = elist[p];
      const float4* fp4 = (const float4*)(ea + (size_t)orig * R + q * 8);
      float4 x0 = fp4[0], x1 = fp4[1];
      pk.x = (unsigned)f2bfu(x0.x) | ((unsigned)f2bfu(x0.y) << 16);
      pk.y = (unsigned)f2bfu(x0.z) | ((unsigned)f2bfu(x0.w) << 16);
      pk.z = (unsigned)f2bfu(x1.x) | ((unsigned)f2bfu(x1.y) << 16);
      pk.w = (unsigned)f2bfu(x1.z) | ((unsigned)f2bfu(x1.w) << 16);
    }
    *(uint4*)&attrW[el * 40 + q * 8] = pk;
  }
  if (l < 16) {
    int p = p0 + l;
    float wgt = 1e9f;
    if (p < E) wgt = ew[elist[p]];
    float cc = 0.5f * (cosf(wgt * (PI_F / CUTOFF)) + 1.0f);
    cws[wv][l] = (wgt < CUTOFF) ? cc : 0.f;
  }
  LDS_FENCE();

  const int g = l >> 4, r = l & 15;
  const short8b* WfL1 = (const short8b*)Wf;
  const short8b* WfL2 = WfL1 + 256;
  const short8b* WfL3 = WfL1 + 1280;

  // ---- layer 1: 32 -> 64 ----
  f32x4 acc1[4];
#pragma unroll
  for (int nt = 0; nt < 4; nt++) {
    float b = b1[nt * 16 + r];
    acc1[nt] = (f32x4){b, b, b, b};
  }
  {
    const unsigned short* arow = attrW + r * 40;
    short4b lo = *(const short4b*)(arow + g * 4);
    short4b hi = *(const short4b*)(arow + 16 + g * 4);
    short8b a = __builtin_shufflevector(lo, hi, 0, 1, 2, 3, 4, 5, 6, 7);
#pragma unroll
    for (int nt = 0; nt < 4; nt++)
      acc1[nt] = __builtin_amdgcn_mfma_f32_16x16x32_bf16(a, WfL1[nt * 64 + l], acc1[nt], 0, 0, 0);
  }
#pragma unroll
  for (int nt = 0; nt < 4; nt++)
#pragma unroll
    for (int reg = 0; reg < 4; reg++)
      h1W[(g * 4 + reg) * 72 + nt * 16 + r] = f2bfu(silu(acc1[nt][reg]));
  LDS_FENCE();

  // ---- layer 2: 64 -> 128 ----
  f32x4 acc2[8];
#pragma unroll
  for (int nt = 0; nt < 8; nt++) {
    float b = b2[nt * 16 + r];
    acc2[nt] = (f32x4){b, b, b, b};
  }
#pragma unroll
  for (int s = 0; s < 2; s++) {
    const unsigned short* hrow = h1W + r * 72 + s * 32;
    short4b lo = *(const short4b*)(hrow + g * 4);
    short4b hi = *(const short4b*)(hrow + 16 + g * 4);
    short8b a = __builtin_shufflevector(lo, hi, 0, 1, 2, 3, 4, 5, 6, 7);
#pragma unroll
    for (int nt = 0; nt < 8; nt++)
      acc2[nt] = __builtin_amdgcn_mfma_f32_16x16x32_bf16(a, WfL2[(s * 8 + nt) * 64 + l], acc2[nt], 0, 0, 0);
  }
#pragma unroll
  for (int nt = 0; nt < 8; nt++)
#pragma unroll
    for (int reg = 0; reg < 4; reg++)
      h2W[(g * 4 + reg) * 136 + nt * 16 + r] = f2bfu(silu(acc2[nt][reg]));
  LDS_FENCE();

  // ---- layer 3: 128 -> 192 ----
  f32x4 acc3[12];
#pragma unroll
  for (int nt = 0; nt < 12; nt++) {
    float b = b3[nt * 16 + r];
    acc3[nt] = (f32x4){b, b, b, b};
  }
#pragma unroll
  for (int s = 0; s < 4; s++) {
    const unsigned short* hrow = h2W + r * 136 + s * 32;
    short4b lo = *(const short4b*)(hrow + g * 4);
    short4b hi = *(const short4b*)(hrow + 16 + g * 4);
    short8b a = __builtin_shufflevector(lo, hi, 0, 1, 2, 3, 4, 5, 6, 7);
#pragma unroll
    for (int nt = 0; nt < 12; nt++)
      acc3[nt] = __builtin_amdgcn_mfma_f32_16x16x32_bf16(a, WfL3[(s * 12 + nt) * 64 + l], acc3[nt], 0, 0, 0);
  }
  LDS_FENCE();   // all reads of attr/h1/h2 done before h3 alias-writes

  // ---- h3 (bf16, *cw) -> LDS, then coalesced repack to fa (CSR order) ----
  {
    float cwr[4];
#pragma unroll
    for (int reg = 0; reg < 4; reg++) cwr[reg] = cws[wv][g * 4 + reg];
#pragma unroll
    for (int nt = 0; nt < 12; nt++) {
      int n = nt * 16 + r;
#pragma unroll
      for (int reg = 0; reg < 4; reg++)
        h3W[(g * 4 + reg) * 200 + n] = f2bfu(silu(acc3[nt][reg]) * cwr[reg]);
    }
  }
  LDS_FENCE();
  {
#pragma unroll
    for (int s2 = 0; s2 < 8; s2++) {
      int gbyte = s2 * 1024 + l * 16;
      int el = gbyte >> 9;
      int off8 = gbyte & 511;
      int ch0 = off8 >> 3;            // always even
      int p = p0 + el;
      if (p < E) {
        const unsigned* hp = (const unsigned*)(h3W + el * 200 + 3 * ch0);
        unsigned u0 = hp[0], u1 = hp[1], u2 = hp[2];
        uint4 v = make_uint4(u0, u1 & 0xffffu, (u1 >> 16) | (u2 << 16), u2 >> 16);
        *(uint4*)((char*)fa + (size_t)p * 512 + off8) = v;
      }
    }
  }
}

// ---------------------------------------------------------------------------
// Fused gather + output. Block = 2 nodes x 2 waves, CSR-sequential fa/dlist
// streams, bf16 nfh random gathers, 2-deep prefetch pipeline. Epilogue
// channel-mix split across both waves.
// ---------------------------------------------------------------------------
__global__ __launch_bounds__(256) void k_gather_out(
    const int* __restrict__ dlist, const int* __restrict__ off,
    const unsigned short* __restrict__ fa, const unsigned* __restrict__ nfh,
    const float* __restrict__ nf32, const float* __restrict__ Xn,
    const float* __restrict__ Wt, float* __restrict__ out, int N) {
  const int wv  = threadIdx.x >> 6;
  const int c   = threadIdx.x & 63;
  const int nl  = wv >> 1, sub = wv & 1;
  const int node = blockIdx.x * 2 + nl;
  __shared__ float part[2][64][10];
  __shared__ float comps[2][C][12];

  float m[9];
#pragma unroll
  for (int j = 0; j < 9; j++) m[j] = 0.f;

  if (node < N) {
    const int t0 = off[node + 1];
    int ip = off[node] + sub;

#define LOADSLOT(ii, F, P0, P1, P2)                                            \
    {                                                                          \
      int _d = dlist[ii];                                                      \
      F = *(const uint2*)((const char*)fa + ((size_t)(ii) << 9) + (c << 3));   \
      const uint2* _np = (const uint2*)(nfh + (size_t)_d * 384 + c * 6);       \
      P0 = _np[0]; P1 = _np[1]; P2 = _np[2];                                   \
    }

    uint2 fA = make_uint2(0, 0), A0 = fA, A1 = fA, A2 = fA;
    uint2 fB = fA, B0 = fA, B1 = fA, B2 = fA;
    if (ip < t0)     LOADSLOT(ip,     fA, A0, A1, A2);
    if (ip + 2 < t0) LOADSLOT(ip + 2, fB, B0, B1, B2);
    for (; ip < t0; ip += 2) {
      int inx = ip + 4;
      uint2 fT = make_uint2(0, 0), T0 = fT, T1 = fT, T2 = fT;
      if (inx < t0) LOADSLOT(inx, fT, T0, T1, T2);
      // unpack + accumulate slot A
      {
        float f0 = bflo(fA.x), f1 = bfhi(fA.x), f2 = bflo(fA.y);
        float iv  = bflo(A0.x), a0  = bfhi(A0.x);
        float a1  = bflo(A0.y), a2  = bfhi(A0.y);
        float s00 = bflo(A1.x), s11 = bfhi(A1.x);
        float s22 = bflo(A1.y), s01 = bfhi(A1.y);
        float s02 = bflo(A2.x), s12 = bfhi(A2.x);
        float d0 = f0 * iv;
        m[0] += d0 + f2 * s00; m[4] += d0 + f2 * s11; m[8] += d0 + f2 * s22;
        float A01 = f1 * a0, A02 = f1 * a1, A12 = f1 * a2;
        float S01 = f2 * s01, S02 = f2 * s02, S12 = f2 * s12;
        m[1] += A01 + S01; m[3] += S01 - A01;
        m[2] += A02 + S02; m[6] += S02 - A02;
        m[5] += A12 + S12; m[7] += S12 - A12;
      }
      fA = fB; A0 = B0; A1 = B1; A2 = B2;
      fB = fT; B0 = T0; B1 = T1; B2 = T2;
    }
#undef LOADSLOT
  }

  if (sub == 1 && node < N) {
#pragma unroll
    for (int j = 0; j < 9; j++) part[nl][c][j] = m[j];
  }
  __syncthreads();
  if (sub == 0 && node < N) {
#pragma unroll
    for (int j = 0; j < 9; j++) m[j] += part[nl][c][j];
    const float* p = nf32 + (size_t)node * 768 + c * 12;
    float4 q0 = *(const float4*)p;
    float4 q1 = *(const float4*)(p + 4);
    float2 q2 = *(const float2*)(p + 8);
    float iv = q0.x, a0 = q0.y, a1 = q0.z, a2 = q0.w;
    float s00 = q1.x, s11 = q1.y, s22 = q1.z, s01 = q1.w;
    float s02 = q2.x, s12 = q2.y;
    float Y[9] = { iv + s00, a0 + s01, a1 + s02,
                   s01 - a0, iv + s11, a2 + s12,
                   s02 - a1, s12 - a2, iv + s22 };
    float M[9];
#pragma unroll
    for (int i2 = 0; i2 < 3; i2++)
#pragma unroll
      for (int j2 = 0; j2 < 3; j2++) {
        float acc = 0.f;
#pragma unroll
        for (int k2 = 0; k2 < 3; k2++)
          acc += m[i2 * 3 + k2] * Y[k2 * 3 + j2] + Y[i2 * 3 + k2] * m[k2 * 3 + j2];
        M[i2 * 3 + j2] = acc;
      }
    float nrm = 0.f;
#pragma unroll
    for (int j = 0; j < 9; j++) nrm += M[j] * M[j];
    const float inv = 1.0f / (nrm + 1.0f);
    const float tr3 = (M[0] + M[4] + M[8]) * (1.f / 3.f);
    float* cp = comps[nl][c];
    cp[0] = tr3 * inv;
    cp[1] = 0.5f * (M[1] - M[3]) * inv;
    cp[2] = 0.5f * (M[2] - M[6]) * inv;
    cp[3] = 0.5f * (M[5] - M[7]) * inv;
    cp[4] = (M[0] - tr3) * inv;
    cp[5] = (M[4] - tr3) * inv;
    cp[6] = (M[8] - tr3) * inv;
    cp[7] = 0.5f * (M[1] + M[3]) * inv;
    cp[8] = 0.5f * (M[2] + M[6]) * inv;
    cp[9] = 0.5f * (M[5] + M[7]) * inv;
  }
  __syncthreads();

  // epilogue channel-mix, split across both waves (k-halves)
  float o[10];
#pragma unroll
  for (int j = 0; j < 10; j++) o[j] = 0.f;
  if (node < N) {
    const float* W3p = Wt + 3 * C * C;
    const float* W4p = Wt + 4 * C * C;
    const float* W5p = Wt + 5 * C * C;
    for (int k = sub * 32; k < sub * 32 + 32; k++) {
      const float w3 = W3p[k * C + c];
      const float w4 = W4p[k * C + c];
      const float w5 = W5p[k * C + c];
      const float4* cq = (const float4*)comps[nl][k];
      float4 q0 = cq[0], q1 = cq[1];
      float2 q2 = *(const float2*)(comps[nl][k] + 8);
      o[0] += q0.x * w3;
      o[1] += q0.y * w4; o[2] += q0.z * w4; o[3] += q0.w * w4;
      o[4] += q1.x * w5; o[5] += q1.y * w5; o[6] += q1.z * w5;
      o[7] += q1.w * w5; o[8] += q2.x * w5; o[9] += q2.y * w5;
    }
  }
  if (sub == 1 && node < N) {
#pragma unroll
    for (int j = 0; j < 10; j++) part[nl][c][j] = o[j];
  }
  __syncthreads();
  if (sub == 0 && node < N) {
#pragma unroll
    for (int j = 0; j < 10; j++) o[j] += part[nl][c][j];
    float dX[9] = { o[0] + o[4], o[1] + o[7], o[2] + o[8],
                    o[7] - o[1], o[0] + o[5], o[3] + o[9],
                    o[8] - o[2], o[9] - o[3], o[0] + o[6] };
    float dd[9];
#pragma unroll
    for (int i2 = 0; i2 < 3; i2++)
#pragma unroll
      for (int j2 = 0; j2 < 3; j2++) {
        float acc = 0.f;
#pragma unroll
        for (int k2 = 0; k2 < 3; k2++) acc += dX[i2 * 3 + k2] * dX[k2 * 3 + j2];
        dd[i2 * 3 + j2] = acc;
      }
    const float* xnp = Xn + (size_t)node * 576 + c;
    float* op = out + ((size_t)node * C + c) * 9;
#pragma unroll
    for (int j = 0; j < 9; j++) op[j] = xnp[j * 64] + dX[j] + dd[j];
  }
}

extern "C" void kernel_launch(void* const* d_in, const int* in_sizes, int n_in,
                              void* d_out, int out_size, void* d_ws, size_t ws_size,
                              hipStream_t stream) {
  const float* X  = (const float*)d_in[0];
  const int*   ei = (const int*)d_in[1];
  const float* ew = (const float*)d_in[2];
  const float* ea = (const float*)d_in[3];
  const float* W1 = (const float*)d_in[4];
  const float* b1 = (const float*)d_in[5];
  const float* W2 = (const float*)d_in[6];
  const float* b2 = (const float*)d_in[7];
  const float* W3 = (const float*)d_in[8];
  const float* b3 = (const float*)d_in[9];
  const float* Wt = (const float*)d_in[10];
  const int N = in_sizes[0] / (C * 9);
  const int E = in_sizes[1] / 2;

  float* nf32 = (float*)d_ws;                                    // [N][C][12]
  float* Xn   = nf32 + (size_t)N * 768;                          // [N][9][C]
  unsigned* nfh = (unsigned*)(Xn + (size_t)N * 576);             // [N][C][6]
  unsigned short* fa = (unsigned short*)(nfh + (size_t)N * 384); // [E][64][4]
  unsigned short* Wf = fa + (size_t)E * 256;                     // 34816
  int* deg  = (int*)(Wf + 34816);                                // [N]
  int* off  = deg + N;                                           // [N+1]
  int* cur  = off + N + 1;                                       // [N]
  int* elist = cur + N;                                          // [E]
  int* dlist = elist + E;                                        // [E]

  const int histB = (E + 255) / 256;
  hipMemsetAsync(deg, 0, (size_t)N * sizeof(int), stream);
  k_misc<<<histB + 136, 256, 0, stream>>>(ei, deg, E, histB, W1, W2, W3, Wf);
  k_node_prep<<<(N + 3) / 4, 256, 0, stream>>>(X, Wt, Xn, nf32, nfh, N);
  k_scan<<<1, 1024, 0, stream>>>(deg, off, cur, N);
  k_fill<<<(E + 255) / 256, 256, 0, stream>>>(ei, off, cur, elist, dlist, E);
  k_mlp<<<(E + 63) / 64, 256, 0, stream>>>(ew, ea, b1, b2, b3, Wf, elist, fa, E);
  k_gather_out<<<(N + 1) / 2, 256, 0, stream>>>(dlist, off, fa, nfh, nf32, Xn, Wt,
                                                (float*)d_out, N);
}

// Round 8
// 190.772 us; speedup vs baseline: 1.1678x; 1.1678x over previous
//
#include <hip/hip_runtime.h>
#include <math.h>

#define C 64
#define R 32
#define CUTOFF 5.0f
#define PI_F 3.14159265358979323846f

typedef __attribute__((ext_vector_type(8))) short short8b;
typedef __attribute__((ext_vector_type(4))) short short4b;
typedef __attribute__((ext_vector_type(4))) float f32x4;

__device__ __forceinline__ float silu(float x) { return x / (1.0f + __expf(-x)); }

__device__ __forceinline__ unsigned short f2bfu(float x) {
  unsigned u = __builtin_bit_cast(unsigned, x);
  u += 0x7FFF + ((u >> 16) & 1);           // round-to-nearest-even
  return (unsigned short)(u >> 16);
}
__device__ __forceinline__ float bflo(unsigned u) {
  return __builtin_bit_cast(float, u << 16);
}
__device__ __forceinline__ float bfhi(unsigned u) {
  return __builtin_bit_cast(float, u & 0xffff0000u);
}
__device__ __forceinline__ unsigned pk2(float a, float b) {
  return (unsigned)f2bfu(a) | ((unsigned)f2bfu(b) << 16);
}

// ---------------------------------------------------------------------------
// Fused: histogram (blocks [0,histB)) + weight prep ([histB,histB+136)) +
// node prep (rest).  W3 is column-permuted to plane order n' = (n%3)*64+n/3.
// ---------------------------------------------------------------------------
__global__ __launch_bounds__(256) void k_misc(
    const int* __restrict__ ei, int* __restrict__ deg, int E, int histB,
    const float* __restrict__ W1, const float* __restrict__ W2,
    const float* __restrict__ W3, unsigned short* __restrict__ Wf,
    const float* __restrict__ X, const float* __restrict__ Wt,
    float* __restrict__ Xn, float* __restrict__ nf32,
    unsigned* __restrict__ nfh, int N) {
  __shared__ float comps[4][C][12];
  const int bid = blockIdx.x;
  if (bid < histB) {
    int e = bid * 256 + threadIdx.x;
    if (e < E) atomicAdd(&deg[ei[e]], 1);
    return;
  }
  if (bid < histB + 136) {
    int id = (bid - histB) * 256 + threadIdx.x;
    if (id >= 34816) return;
    int i, l, t;
    if (id < 2048) {
      i = id & 7; l = (id >> 3) & 63; t = id >> 9;
      int nt = t % 4, ks = t / 4;
      int k = ks * 32 + ((l >> 4) << 2) + (i & 3) + ((i >> 2) << 4);
      int n = nt * 16 + (l & 15);
      Wf[id] = f2bfu(W1[(size_t)k * 64 + n]);
    } else if (id < 10240) {
      int id2 = id - 2048;
      i = id2 & 7; l = (id2 >> 3) & 63; t = id2 >> 9;
      int nt = t % 8, ks = t / 8;
      int k = ks * 32 + ((l >> 4) << 2) + (i & 3) + ((i >> 2) << 4);
      int n = nt * 16 + (l & 15);
      Wf[id] = f2bfu(W2[(size_t)k * 128 + n]);
    } else {
      int id2 = id - 10240;
      i = id2 & 7; l = (id2 >> 3) & 63; t = id2 >> 9;
      int nt = t % 12, ks = t / 12;
      int k = ks * 32 + ((l >> 4) << 2) + (i & 3) + ((i >> 2) << 4);
      int nperm = nt * 16 + (l & 15);            // plane order
      int norig = (nperm & 63) * 3 + (nperm >> 6);
      Wf[id] = f2bfu(W3[(size_t)k * 192 + norig]);
    }
    return;
  }
  // ---- node prep ----
  const int ln = threadIdx.x >> 6;
  const int c  = threadIdx.x & 63;
  const int node = (bid - histB - 136) * 4 + ln;
  if (node < N) {
    const float* xp = X + ((size_t)node * C + c) * 9;
    float x[9]; float nrm = 0.f;
#pragma unroll
    for (int j = 0; j < 9; j++) { x[j] = xp[j]; nrm += x[j] * x[j]; }
    const float inv = 1.0f / (nrm + 1.0f);
#pragma unroll
    for (int j = 0; j < 9; j++) x[j] *= inv;
    float* xnp = Xn + (size_t)node * 576 + c;
#pragma unroll
    for (int j = 0; j < 9; j++) xnp[j * 64] = x[j];
    const float tr3 = (x[0] + x[4] + x[8]) * (1.f / 3.f);
    float* cp = comps[ln][c];
    cp[0] = tr3;
    cp[1] = 0.5f * (x[1] - x[3]);
    cp[2] = 0.5f * (x[2] - x[6]);
    cp[3] = 0.5f * (x[5] - x[7]);
    cp[4] = x[0] - tr3;
    cp[5] = x[4] - tr3;
    cp[6] = x[8] - tr3;
    cp[7] = 0.5f * (x[1] + x[3]);
    cp[8] = 0.5f * (x[2] + x[6]);
    cp[9] = 0.5f * (x[5] + x[7]);
  }
  __syncthreads();
  if (node < N) {
    const float* W0 = Wt;
    const float* Wt1 = Wt + C * C;
    const float* Wt2 = Wt + 2 * C * C;
    float o[10];
#pragma unroll
    for (int j = 0; j < 10; j++) o[j] = 0.f;
    for (int k = 0; k < C; k++) {
      const float w0 = W0[k * C + c];
      const float w1 = Wt1[k * C + c];
      const float w2 = Wt2[k * C + c];
      const float4* cq = (const float4*)comps[ln][k];
      float4 q0 = cq[0], q1 = cq[1];
      float2 q2 = *(const float2*)(comps[ln][k] + 8);
      o[0] += q0.x * w0;
      o[1] += q0.y * w1; o[2] += q0.z * w1; o[3] += q0.w * w1;
      o[4] += q1.x * w2; o[5] += q1.y * w2; o[6] += q1.z * w2;
      o[7] += q1.w * w2; o[8] += q2.x * w2; o[9] += q2.y * w2;
    }
    float* np_ = nf32 + (size_t)node * 768 + c * 12;
    *(float4*)np_       = make_float4(o[0], o[1], o[2], o[3]);
    *(float4*)(np_ + 4) = make_float4(o[4], o[5], o[6], o[7]);
    *(float4*)(np_ + 8) = make_float4(o[8], o[9], 0.f, 0.f);
    unsigned* hp = nfh + (size_t)node * 384 + c * 6;
    *(uint2*)hp       = make_uint2(pk2(o[0], o[1]), pk2(o[2], o[3]));
    *(uint2*)(hp + 2) = make_uint2(pk2(o[4], o[5]), pk2(o[6], o[7]));
    *(uint2*)(hp + 4) = make_uint2(pk2(o[8], o[9]), 0u);
  }
}

// ---------------------------------------------------------------------------
// CSR build.
// ---------------------------------------------------------------------------
__global__ __launch_bounds__(1024) void k_scan(const int* __restrict__ deg,
                                               int* __restrict__ off,
                                               int* __restrict__ cur, int N) {
  __shared__ int sums[1024];
  const int t = threadIdx.x;
  const int L = (N + 1023) / 1024;
  const int base = t * L;
  int s = 0;
  for (int j = 0; j < L; j++) if (base + j < N) s += deg[base + j];
  sums[t] = s;
  __syncthreads();
  for (int d = 1; d < 1024; d <<= 1) {
    int v = (t >= d) ? sums[t - d] : 0;
    __syncthreads();
    sums[t] += v;
    __syncthreads();
  }
  int run = (t > 0) ? sums[t - 1] : 0;
  for (int j = 0; j < L; j++) {
    int i = base + j;
    if (i < N) { off[i] = run; run += deg[i]; cur[i] = 0; }
  }
  if (t == 1023) off[N] = sums[1023];
}

__global__ __launch_bounds__(256) void k_fill(const int* __restrict__ ei,
                                              const int* __restrict__ off,
                                              int* __restrict__ cur,
                                              int* __restrict__ elist,
                                              int* __restrict__ dlist, int E) {
  int e = blockIdx.x * 256 + threadIdx.x;
  if (e < E) {
    int s = ei[e];
    int d = ei[E + e];
    int pos = off[s] + atomicAdd(&cur[s], 1);
    elist[pos] = e;
    dlist[pos] = d;
  }
}

// ---------------------------------------------------------------------------
// Edge MLP via MFMA bf16, N-split waves, NO transpose reads.
// Key identity: A and B fragment layouts are lane-symmetric for 16x16x32
// (A: m=lane&15; B: n=lane&15; same k-mapping), so:
//  - L1/L2 use SWAPPED operands: D = mfma(Wfrag, edgefrag) = D[outcol][edge].
//    Lane (g,r) holds 4 consecutive outcols for edge r -> ONE packed uint2
//    write into M-major h[edge][k], which the next layer reads with the
//    verified row-fragment pattern.
//  - L3 non-swapped with plane-permuted W3: D col = fixed channel per lane
//    -> coalesced uint2 stores straight to fa[p][64][4].
// ---------------------------------------------------------------------------
__global__ __launch_bounds__(256) void k_mlp(
    const float* __restrict__ ew, const float* __restrict__ ea,
    const float* __restrict__ b1, const float* __restrict__ b2,
    const float* __restrict__ b3, const unsigned short* __restrict__ Wf,
    const int* __restrict__ elist, unsigned short* __restrict__ fa, int E) {
  __shared__ __align__(16) unsigned short attrB[64][40];
  __shared__ __align__(16) unsigned short h1B[64][72];
  __shared__ __align__(16) unsigned short h2B[64][136];
  __shared__ float cws[64];
  const int tid = threadIdx.x;
  const int p0 = blockIdx.x * 64;

  { // stage edge_attr (CSR order) -> bf16 LDS rows (4 lanes/edge)
    int el = tid >> 2, q = tid & 3;
    int p = p0 + el;
    uint4 pk = make_uint4(0, 0, 0, 0);
    if (p < E) {
      int orig = elist[p];
      const float4* fp4 = (const float4*)(ea + (size_t)orig * R + q * 8);
      float4 x0 = fp4[0], x1 = fp4[1];
      pk.x = pk2(x0.x, x0.y); pk.y = pk2(x0.z, x0.w);
      pk.z = pk2(x1.x, x1.y); pk.w = pk2(x1.z, x1.w);
    }
    *(uint4*)&attrB[el][q * 8] = pk;
  }
  if (tid < 64) {
    int p = p0 + tid;
    float wgt = 1e9f;
    if (p < E) wgt = ew[elist[p]];
    float cc = 0.5f * (cosf(wgt * (PI_F / CUTOFF)) + 1.0f);
    cws[tid] = (wgt < CUTOFF) ? cc : 0.f;
  }
  __syncthreads();

  const int wv = tid >> 6, l = tid & 63;
  const int g = l >> 4, r = l & 15;
  const short8b* WfL1 = (const short8b*)Wf;
  const short8b* WfL2 = WfL1 + 256;
  const short8b* WfL3 = WfL1 + 1280;

  // ---- layer 1 (swapped): wave w computes outcols [16w, 16w+16) ----
  {
    short8b w1f = WfL1[wv * 64 + l];
    float4 bb = *(const float4*)(b1 + wv * 16 + g * 4);
    f32x4 binit = (f32x4){bb.x, bb.y, bb.z, bb.w};
#pragma unroll
    for (int t = 0; t < 4; t++) {
      const unsigned short* arow = &attrB[t * 16 + r][0];
      short4b lo = *(const short4b*)(arow + g * 4);
      short4b hi = *(const short4b*)(arow + 16 + g * 4);
      short8b efrag = __builtin_shufflevector(lo, hi, 0, 1, 2, 3, 4, 5, 6, 7);
      f32x4 acc = binit;
      acc = __builtin_amdgcn_mfma_f32_16x16x32_bf16(w1f, efrag, acc, 0, 0, 0);
      uint2 v = make_uint2(pk2(silu(acc[0]), silu(acc[1])),
                           pk2(silu(acc[2]), silu(acc[3])));
      *(uint2*)&h1B[t * 16 + r][wv * 16 + g * 4] = v;
    }
  }
  __syncthreads();

  // ---- layer 2 (swapped): wave w computes outcols [32w, 32w+32) ----
  {
    short8b w2f[2][2];
#pragma unroll
    for (int ks = 0; ks < 2; ks++)
#pragma unroll
      for (int j = 0; j < 2; j++)
        w2f[ks][j] = WfL2[(ks * 8 + 2 * wv + j) * 64 + l];
    float4 bA = *(const float4*)(b2 + (2 * wv) * 16 + g * 4);
    float4 bB = *(const float4*)(b2 + (2 * wv + 1) * 16 + g * 4);
    f32x4 biA = (f32x4){bA.x, bA.y, bA.z, bA.w};
    f32x4 biB = (f32x4){bB.x, bB.y, bB.z, bB.w};
#pragma unroll
    for (int t = 0; t < 4; t++) {
      f32x4 aA = biA, aB = biB;
      const unsigned short* hrow = &h1B[t * 16 + r][0];
#pragma unroll
      for (int ks = 0; ks < 2; ks++) {
        short4b lo = *(const short4b*)(hrow + ks * 32 + g * 4);
        short4b hi = *(const short4b*)(hrow + ks * 32 + 16 + g * 4);
        short8b efrag = __builtin_shufflevector(lo, hi, 0, 1, 2, 3, 4, 5, 6, 7);
        aA = __builtin_amdgcn_mfma_f32_16x16x32_bf16(w2f[ks][0], efrag, aA, 0, 0, 0);
        aB = __builtin_amdgcn_mfma_f32_16x16x32_bf16(w2f[ks][1], efrag, aB, 0, 0, 0);
      }
      uint2 vA = make_uint2(pk2(silu(aA[0]), silu(aA[1])),
                            pk2(silu(aA[2]), silu(aA[3])));
      uint2 vB = make_uint2(pk2(silu(aB[0]), silu(aB[1])),
                            pk2(silu(aB[2]), silu(aB[3])));
      *(uint2*)&h2B[t * 16 + r][(2 * wv) * 16 + g * 4] = vA;
      *(uint2*)&h2B[t * 16 + r][(2 * wv + 1) * 16 + g * 4] = vB;
    }
  }
  __syncthreads();

  // ---- layer 3 (non-swapped, plane-permuted W3): wave w owns channel
  //      ch = 16w + r across planes j=0,1,2 (n-tiles {w, 4+w, 8+w}) ----
  {
    short8b w3f[4][3];
#pragma unroll
    for (int ks = 0; ks < 4; ks++)
#pragma unroll
      for (int j = 0; j < 3; j++)
        w3f[ks][j] = WfL3[(ks * 12 + j * 4 + wv) * 64 + l];
    const int ch = wv * 16 + r;
    float bb0 = b3[ch * 3 + 0];
    float bb1 = b3[ch * 3 + 1];
    float bb2v = b3[ch * 3 + 2];
#pragma unroll
    for (int t = 0; t < 4; t++) {
      f32x4 p0v = (f32x4){bb0, bb0, bb0, bb0};
      f32x4 p1v = (f32x4){bb1, bb1, bb1, bb1};
      f32x4 p2v = (f32x4){bb2v, bb2v, bb2v, bb2v};
      const unsigned short* hrow = &h2B[t * 16 + r][0];
#pragma unroll
      for (int ks = 0; ks < 4; ks++) {
        short4b lo = *(const short4b*)(hrow + ks * 32 + g * 4);
        short4b hi = *(const short4b*)(hrow + ks * 32 + 16 + g * 4);
        short8b a = __builtin_shufflevector(lo, hi, 0, 1, 2, 3, 4, 5, 6, 7);
        p0v = __builtin_amdgcn_mfma_f32_16x16x32_bf16(a, w3f[ks][0], p0v, 0, 0, 0);
        p1v = __builtin_amdgcn_mfma_f32_16x16x32_bf16(a, w3f[ks][1], p1v, 0, 0, 0);
        p2v = __builtin_amdgcn_mfma_f32_16x16x32_bf16(a, w3f[ks][2], p2v, 0, 0, 0);
      }
#pragma unroll
      for (int reg = 0; reg < 4; reg++) {
        int el = t * 16 + g * 4 + reg;
        int p = p0 + el;
        float cw = cws[el];
        uint2 v = make_uint2(pk2(silu(p0v[reg]) * cw, silu(p1v[reg]) * cw),
                             pk2(silu(p2v[reg]) * cw, 0.f));
        if (p < E) *(uint2*)((char*)fa + (size_t)p * 512 + ch * 8) = v;
      }
    }
  }
}

// ---------------------------------------------------------------------------
// Fused gather + output (unchanged).
// ---------------------------------------------------------------------------
__global__ __launch_bounds__(256) void k_gather_out(
    const int* __restrict__ dlist, const int* __restrict__ off,
    const unsigned short* __restrict__ fa, const unsigned* __restrict__ nfh,
    const float* __restrict__ nf32, const float* __restrict__ Xn,
    const float* __restrict__ Wt, float* __restrict__ out, int N) {
  const int wv  = threadIdx.x >> 6;
  const int c   = threadIdx.x & 63;
  const int nl  = wv >> 1, sub = wv & 1;
  const int node = blockIdx.x * 2 + nl;
  __shared__ float part[2][64][10];
  __shared__ float comps[2][C][12];

  float m[9];
#pragma unroll
  for (int j = 0; j < 9; j++) m[j] = 0.f;

  if (node < N) {
    const int t0 = off[node + 1];
    int ip = off[node] + sub;

#define LOADSLOT(ii, F, P0, P1, P2)                                            \
    {                                                                          \
      int _d = dlist[ii];                                                      \
      F = *(const uint2*)((const char*)fa + ((size_t)(ii) << 9) + (c << 3));   \
      const uint2* _np = (const uint2*)(nfh + (size_t)_d * 384 + c * 6);       \
      P0 = _np[0]; P1 = _np[1]; P2 = _np[2];                                   \
    }

    uint2 fA = make_uint2(0, 0), A0 = fA, A1 = fA, A2 = fA;
    uint2 fB = fA, B0 = fA, B1 = fA, B2 = fA;
    if (ip < t0)     LOADSLOT(ip,     fA, A0, A1, A2);
    if (ip + 2 < t0) LOADSLOT(ip + 2, fB, B0, B1, B2);
    for (; ip < t0; ip += 2) {
      int inx = ip + 4;
      uint2 fT = make_uint2(0, 0), T0 = fT, T1 = fT, T2 = fT;
      if (inx < t0) LOADSLOT(inx, fT, T0, T1, T2);
      {
        float f0 = bflo(fA.x), f1 = bfhi(fA.x), f2 = bflo(fA.y);
        float iv  = bflo(A0.x), a0  = bfhi(A0.x);
        float a1  = bflo(A0.y), a2  = bfhi(A0.y);
        float s00 = bflo(A1.x), s11 = bfhi(A1.x);
        float s22 = bflo(A1.y), s01 = bfhi(A1.y);
        float s02 = bflo(A2.x), s12 = bfhi(A2.x);
        float d0 = f0 * iv;
        m[0] += d0 + f2 * s00; m[4] += d0 + f2 * s11; m[8] += d0 + f2 * s22;
        float A01 = f1 * a0, A02 = f1 * a1, A12 = f1 * a2;
        float S01 = f2 * s01, S02 = f2 * s02, S12 = f2 * s12;
        m[1] += A01 + S01; m[3] += S01 - A01;
        m[2] += A02 + S02; m[6] += S02 - A02;
        m[5] += A12 + S12; m[7] += S12 - A12;
      }
      fA = fB; A0 = B0; A1 = B1; A2 = B2;
      fB = fT; B0 = T0; B1 = T1; B2 = T2;
    }
#undef LOADSLOT
  }

  if (sub == 1 && node < N) {
#pragma unroll
    for (int j = 0; j < 9; j++) part[nl][c][j] = m[j];
  }
  __syncthreads();
  if (sub == 0 && node < N) {
#pragma unroll
    for (int j = 0; j < 9; j++) m[j] += part[nl][c][j];
    const float* p = nf32 + (size_t)node * 768 + c * 12;
    float4 q0 = *(const float4*)p;
    float4 q1 = *(const float4*)(p + 4);
    float2 q2 = *(const float2*)(p + 8);
    float iv = q0.x, a0 = q0.y, a1 = q0.z, a2 = q0.w;
    float s00 = q1.x, s11 = q1.y, s22 = q1.z, s01 = q1.w;
    float s02 = q2.x, s12 = q2.y;
    float Y[9] = { iv + s00, a0 + s01, a1 + s02,
                   s01 - a0, iv + s11, a2 + s12,
                   s02 - a1, s12 - a2, iv + s22 };
    float M[9];
#pragma unroll
    for (int i2 = 0; i2 < 3; i2++)
#pragma unroll
      for (int j2 = 0; j2 < 3; j2++) {
        float acc = 0.f;
#pragma unroll
        for (int k2 = 0; k2 < 3; k2++)
          acc += m[i2 * 3 + k2] * Y[k2 * 3 + j2] + Y[i2 * 3 + k2] * m[k2 * 3 + j2];
        M[i2 * 3 + j2] = acc;
      }
    float nrm = 0.f;
#pragma unroll
    for (int j = 0; j < 9; j++) nrm += M[j] * M[j];
    const float inv = 1.0f / (nrm + 1.0f);
    const float tr3 = (M[0] + M[4] + M[8]) * (1.f / 3.f);
    float* cp = comps[nl][c];
    cp[0] = tr3 * inv;
    cp[1] = 0.5f * (M[1] - M[3]) * inv;
    cp[2] = 0.5f * (M[2] - M[6]) * inv;
    cp[3] = 0.5f * (M[5] - M[7]) * inv;
    cp[4] = (M[0] - tr3) * inv;
    cp[5] = (M[4] - tr3) * inv;
    cp[6] = (M[8] - tr3) * inv;
    cp[7] = 0.5f * (M[1] + M[3]) * inv;
    cp[8] = 0.5f * (M[2] + M[6]) * inv;
    cp[9] = 0.5f * (M[5] + M[7]) * inv;
  }
  __syncthreads();

  float o[10];
#pragma unroll
  for (int j = 0; j < 10; j++) o[j] = 0.f;
  if (node < N) {
    const float* W3p = Wt + 3 * C * C;
    const float* W4p = Wt + 4 * C * C;
    const float* W5p = Wt + 5 * C * C;
    for (int k = sub * 32; k < sub * 32 + 32; k++) {
      const float w3 = W3p[k * C + c];
      const float w4 = W4p[k * C + c];
      const float w5 = W5p[k * C + c];
      const float4* cq = (const float4*)comps[nl][k];
      float4 q0 = cq[0], q1 = cq[1];
      float2 q2 = *(const float2*)(comps[nl][k] + 8);
      o[0] += q0.x * w3;
      o[1] += q0.y * w4; o[2] += q0.z * w4; o[3] += q0.w * w4;
      o[4] += q1.x * w5; o[5] += q1.y * w5; o[6] += q1.z * w5;
      o[7] += q1.w * w5; o[8] += q2.x * w5; o[9] += q2.y * w5;
    }
  }
  if (sub == 1 && node < N) {
#pragma unroll
    for (int j = 0; j < 10; j++) part[nl][c][j] = o[j];
  }
  __syncthreads();
  if (sub == 0 && node < N) {
#pragma unroll
    for (int j = 0; j < 10; j++) o[j] += part[nl][c][j];
    float dX[9] = { o[0] + o[4], o[1] + o[7], o[2] + o[8],
                    o[7] - o[1], o[0] + o[5], o[3] + o[9],
                    o[8] - o[2], o[9] - o[3], o[0] + o[6] };
    float dd[9];
#pragma unroll
    for (int i2 = 0; i2 < 3; i2++)
#pragma unroll
      for (int j2 = 0; j2 < 3; j2++) {
        float acc = 0.f;
#pragma unroll
        for (int k2 = 0; k2 < 3; k2++) acc += dX[i2 * 3 + k2] * dX[k2 * 3 + j2];
        dd[i2 * 3 + j2] = acc;
      }
    const float* xnp = Xn + (size_t)node * 576 + c;
    float* op = out + ((size_t)node * C + c) * 9;
#pragma unroll
    for (int j = 0; j < 9; j++) op[j] = xnp[j * 64] + dX[j] + dd[j];
  }
}

extern "C" void kernel_launch(void* const* d_in, const int* in_sizes, int n_in,
                              void* d_out, int out_size, void* d_ws, size_t ws_size,
                              hipStream_t stream) {
  const float* X  = (const float*)d_in[0];
  const int*   ei = (const int*)d_in[1];
  const float* ew = (const float*)d_in[2];
  const float* ea = (const float*)d_in[3];
  const float* W1 = (const float*)d_in[4];
  const float* b1 = (const float*)d_in[5];
  const float* W2 = (const float*)d_in[6];
  const float* b2 = (const float*)d_in[7];
  const float* W3 = (const float*)d_in[8];
  const float* b3 = (const float*)d_in[9];
  const float* Wt = (const float*)d_in[10];
  const int N = in_sizes[0] / (C * 9);
  const int E = in_sizes[1] / 2;

  float* nf32 = (float*)d_ws;                                    // [N][C][12]
  float* Xn   = nf32 + (size_t)N * 768;                          // [N][9][C]
  unsigned* nfh = (unsigned*)(Xn + (size_t)N * 576);             // [N][C][6]
  unsigned short* fa = (unsigned short*)(nfh + (size_t)N * 384); // [E][64][4]
  unsigned short* Wf = fa + (size_t)E * 256;                     // 34816
  int* deg  = (int*)(Wf + 34816);                                // [N]
  int* off  = deg + N;                                           // [N+1]
  int* cur  = off + N + 1;                                       // [N]
  int* elist = cur + N;                                          // [E]
  int* dlist = elist + E;                                        // [E]

  const int histB = (E + 255) / 256;
  const int nodeB = (N + 3) / 4;
  (void)hipMemsetAsync(deg, 0, (size_t)N * sizeof(int), stream);
  k_misc<<<histB + 136 + nodeB, 256, 0, stream>>>(ei, deg, E, histB,
                                                  W1, W2, W3, Wf,
                                                  X, Wt, Xn, nf32, nfh, N);
  k_scan<<<1, 1024, 0, stream>>>(deg, off, cur, N);
  k_fill<<<(E + 255) / 256, 256, 0, stream>>>(ei, off, cur, elist, dlist, E);
  k_mlp<<<(E + 63) / 64, 256, 0, stream>>>(ew, ea, b1, b2, b3, Wf, elist, fa, E);
  k_gather_out<<<(N + 1) / 2, 256, 0, stream>>>(dlist, off, fa, nfh, nf32, Xn, Wt,
                                                (float*)d_out, N);
}